// Round 4
// baseline (3785.245 us; speedup 1.0000x reference)
//
#include <hip/hip_runtime.h>
#include <math.h>

#define NE 50000
#define R2C 480
#define DD 200
#define TT 4
#define EE 100000
#define SLOPE 0.22916666666666666f

#define SCCH 8            // edges per thread in binned kernels
#define EPB (256 * SCCH)  // edges per block = 2048
#define APAD 224          // padded bf16 row stride for agg (multiple of 32)
#define WPAD 224          // padded bf16 k-stride for pre-converted weights
#define WSZ (208 * WPAD)  // one pre-converted weight matrix (shorts)
#define DCH 4096          // deg-scan chunk (256 threads x 16)
#define DNC ((NE + DCH - 1) / DCH)  // 13
#define NTILE 3125        // 50000 / 16 row-tiles

typedef short short8 __attribute__((ext_vector_type(8)));
typedef float float4v __attribute__((ext_vector_type(4)));

__device__ __forceinline__ float sigm(float x) { return 1.f / (1.f + expf(-x)); }

__device__ __forceinline__ short f2bf(float f) {  // fp32 -> bf16 RNE
  union { float f; unsigned u; } v;
  v.f = f;
  unsigned r = v.u + 0x7fffu + ((v.u >> 16) & 1u);
  return (short)(r >> 16);
}

// ---------- setup kernels ----------

__global__ void init_h_kernel(const float* __restrict__ emb, float* __restrict__ h) {
  int n = blockIdx.x;            // one 64-lane wave per row
  int lane = threadIdx.x;
  size_t base = (size_t)n * DD;
  float v0 = emb[base + lane];
  float v1 = emb[base + 64 + lane];
  float v2 = emb[base + 128 + lane];
  float v3 = (lane < 8) ? emb[base + 192 + lane] : 0.f;
  float ss = v0 * v0 + v1 * v1 + v2 * v2 + v3 * v3;
#pragma unroll
  for (int off = 32; off; off >>= 1) ss += __shfl_down(ss, off);
  ss = __shfl(ss, 0);
  float inv = 1.f / fmaxf(sqrtf(ss), 1e-12f);
  h[base + lane] = v0 * inv;
  h[base + 64 + lane] = v1 * inv;
  h[base + 128 + lane] = v2 * inv;
  if (lane < 8) h[base + 192 + lane] = v3 * inv;
}

__global__ void copy_kernel(const float* __restrict__ a, float* __restrict__ b, int n) {
  int i = blockIdx.x * blockDim.x + threadIdx.x;
  if (i < n) b[i] = a[i];
}

// X[r][0:200] = emb_rel[r]  (X row stride 400)
__global__ void fill_x_kernel(const float* __restrict__ emb_rel, float* __restrict__ X) {
  int i = blockIdx.x * blockDim.x + threadIdx.x;
  if (i >= R2C * DD) return;
  int r = i / DD, d = i - r * DD;
  X[(size_t)r * 400 + d] = emb_rel[i];
}

// pre-convert 5 weight matrices to bf16, layout [m][n(208)][k(224)], zero-padded
__global__ void prep_w_kernel(const float* __restrict__ Wnb, const float* __restrict__ Wlp,
                              const float* __restrict__ Wtg, short* __restrict__ Wb) {
  int idx = blockIdx.x * 256 + threadIdx.x;
  if (idx >= 5 * WSZ) return;
  int m = idx / WSZ, rem = idx - m * WSZ;
  int n = rem / WPAD, k = rem - n * WPAD;
  const float* s;
  if (m == 0) s = Wnb;
  else if (m == 1) s = Wnb + DD * DD;
  else if (m == 2) s = Wlp;
  else if (m == 3) s = Wlp + DD * DD;
  else s = Wtg;
  float v = (n < DD && k < DD) ? s[(size_t)k * DD + n] : 0.f;
  Wb[idx] = f2bf(v);
}

// LDS-binned et histogram; deg_hist stays global (50k bins, low contention)
__global__ __launch_bounds__(256) void hist_kernel(const int* __restrict__ et,
                                                   const int* __restrict__ dst,
                                                   int* __restrict__ et_hist,
                                                   int* __restrict__ deg_hist) {
  __shared__ int lh[R2C];
  int t = blockIdx.y;
  int tid = threadIdx.x;
  int e0 = blockIdx.x * EPB;
  for (int i = tid; i < R2C; i += 256) lh[i] = 0;
  __syncthreads();
#pragma unroll
  for (int c = 0; c < SCCH; c++) {
    int e = e0 + c * 256 + tid;
    if (e < EE) {
      atomicAdd(&lh[et[(size_t)t * EE + e]], 1);
      atomicAdd(&deg_hist[(size_t)t * NE + dst[(size_t)t * EE + e]], 1);
    }
  }
  __syncthreads();
  for (int i = tid; i < R2C; i += 256)
    if (lh[i]) atomicAdd(&et_hist[t * R2C + i], lh[i]);
}

__global__ void scan_rel_kernel(const int* __restrict__ et_hist, int* __restrict__ rowptr) {
  int t = blockIdx.x;
  int tid = threadIdx.x;  // block 512
  __shared__ int s[512];
  int v = (tid < R2C) ? 2 * et_hist[t * R2C + tid] : 0;
  s[tid] = v;
  __syncthreads();
  for (int off = 1; off < 512; off <<= 1) {
    int x = (tid >= off) ? s[tid - off] : 0;
    __syncthreads();
    s[tid] += x;
    __syncthreads();
  }
  if (tid < R2C) rowptr[t * (R2C + 1) + tid] = s[tid] - v;
  if (tid == 0) rowptr[t * (R2C + 1) + R2C] = 2 * EE;
}

// ---- parallel dst-degree scan: chunk sums, then per-chunk emit ----
__global__ __launch_bounds__(256) void deg_partial_kernel(const int* __restrict__ deg_hist,
                                                          int* __restrict__ csum) {
  int t = blockIdx.y, c = blockIdx.x, tid = threadIdx.x;
  const int* dh = deg_hist + (size_t)t * NE;
  int base = c * DCH + tid * 16;
  int s = 0;
  if (base < NE) {
    int end = base + 16 > NE ? NE : base + 16;
    for (int i = base; i < end; i++) s += dh[i];
  }
  __shared__ int red[256];
  red[tid] = s;
  __syncthreads();
  for (int off = 128; off; off >>= 1) {
    if (tid < off) red[tid] += red[tid + off];
    __syncthreads();
  }
  if (tid == 0) csum[t * DNC + c] = red[0];
}

__global__ __launch_bounds__(256) void deg_emit_kernel(const int* __restrict__ deg_hist,
                                                       const int* __restrict__ csum,
                                                       int* __restrict__ rowptr,
                                                       float* __restrict__ normv) {
  int t = blockIdx.y, c = blockIdx.x, tid = threadIdx.x;
  const int* dh = deg_hist + (size_t)t * NE;
  __shared__ int scan[256];
  __shared__ int soff;
  int base = c * DCH + tid * 16;
  int s = 0;
  if (base < NE) {
    int end = base + 16 > NE ? NE : base + 16;
    for (int i = base; i < end; i++) s += dh[i];
  }
  scan[tid] = s;
  __syncthreads();
  for (int off = 1; off < 256; off <<= 1) {
    int x = (tid >= off) ? scan[tid - off] : 0;
    __syncthreads();
    scan[tid] += x;
    __syncthreads();
  }
  if (tid == 0) {
    int o = 0;
    for (int j = 0; j < c; j++) o += csum[t * DNC + j];
    soff = o;
  }
  __syncthreads();
  int run = soff + scan[tid] - s;
  if (base < NE) {
    int end = base + 16 > NE ? NE : base + 16;
    for (int i = base; i < end; i++) {
      int v = dh[i];
      rowptr[t * (NE + 1) + i] = run;
      normv[(size_t)t * NE + i] = 1.f / fmaxf((float)v, 1.f);
      run += v;
    }
  }
  if (c == 0 && tid == 0) rowptr[t * (NE + 1) + NE] = EE;
}

// LDS-binned scatter: one global atomic per (block, present relation)
__global__ __launch_bounds__(256) void scatter_rel_kernel(const int* __restrict__ src,
                                                          const int* __restrict__ dst,
                                                          const int* __restrict__ et,
                                                          const int* __restrict__ rowptr,
                                                          int* __restrict__ cursor,
                                                          int* __restrict__ sorted_ent) {
  __shared__ int lcnt[R2C];
  __shared__ int lbase[R2C];
  int t = blockIdx.y;
  int tid = threadIdx.x;
  int e0 = blockIdx.x * EPB;
  for (int i = tid; i < R2C; i += 256) lcnt[i] = 0;
  __syncthreads();
  int rels[SCCH];
#pragma unroll
  for (int c = 0; c < SCCH; c++) {
    int e = e0 + c * 256 + tid;
    int r = (e < EE) ? et[(size_t)t * EE + e] : -1;
    rels[c] = r;
    if (r >= 0) atomicAdd(&lcnt[r], 2);
  }
  __syncthreads();
  const int* rp = rowptr + t * (R2C + 1);
  for (int i = tid; i < R2C; i += 256) {
    int c = lcnt[i];
    lbase[i] = rp[i] + (c ? atomicAdd(&cursor[t * R2C + i], c) : 0);
    lcnt[i] = 0;
  }
  __syncthreads();
  int* se = sorted_ent + (size_t)t * 2 * EE;
#pragma unroll
  for (int c = 0; c < SCCH; c++) {
    int r = rels[c];
    if (r >= 0) {
      int e = e0 + c * 256 + tid;
      int off = atomicAdd(&lcnt[r], 2);
      int p = lbase[r] + off;
      se[p] = src[(size_t)t * EE + e];
      se[p + 1] = dst[(size_t)t * EE + e];
    }
  }
}

__global__ void scatter_dst_kernel(const int* __restrict__ dst, const int* __restrict__ rowptr,
                                   int* __restrict__ cursor, int* __restrict__ sorted_edge) {
  int i = blockIdx.x * blockDim.x + threadIdx.x;
  if (i >= TT * EE) return;
  int t = i / EE, e = i - t * EE;
  int d = dst[i];
  int base = rowptr[t * (NE + 1) + d];
  int p = base + atomicAdd(&cursor[(size_t)t * NE + d], 1);
  sorted_edge[(size_t)t * EE + p] = e;
}

// ---------- per-step kernels ----------

// 4 blocks per relation (16 waves): partial sums of h rows -> Xpart[r*4+j][200]
__global__ void relmean_part_kernel(const float* __restrict__ h, const int* __restrict__ rowptr,
                                    const int* __restrict__ sorted_ent_t,
                                    float* __restrict__ Xpart) {
  int r = blockIdx.x, j = blockIdx.y;
  int beg = rowptr[r], end = rowptr[r + 1];
  int lane = threadIdx.x & 63, w = threadIdx.x >> 6;
  float a0 = 0, a1 = 0, a2 = 0, a3 = 0;
  for (int i = beg + j * 4 + w; i < end; i += 16) {
    int idx = sorted_ent_t[i];
    const float* row = h + (size_t)idx * DD;
    a0 += row[lane];
    a1 += row[64 + lane];
    a2 += row[128 + lane];
    if (lane < 8) a3 += row[192 + lane];
  }
  __shared__ float part[4][DD];
  part[w][lane] = a0;
  part[w][64 + lane] = a1;
  part[w][128 + lane] = a2;
  if (lane < 8) part[w][192 + lane] = a3;
  __syncthreads();
  for (int d = threadIdx.x; d < DD; d += 256) {
    Xpart[((size_t)r * 4 + j) * DD + d] = part[0][d] + part[1][d] + part[2][d] + part[3][d];
  }
}

__global__ void relmean_comb_kernel(const float* __restrict__ Xpart,
                                    const int* __restrict__ rowptr, float* __restrict__ X) {
  int r = blockIdx.x;
  int d = threadIdx.x;  // 256
  if (d >= DD) return;
  float s = 0.f;
#pragma unroll
  for (int j = 0; j < 4; j++) s += Xpart[((size_t)r * 4 + j) * DD + d];
  float cnt = fmaxf((float)(rowptr[r + 1] - rowptr[r]), 1.f);
  X[(size_t)r * 400 + 200 + d] = s / cnt;
}

// C[M,N] = A[M,K] @ B[N,K]^T  (B row-major [N,K]); tile 32x32, K-chunk 16, 2x2/thread
__global__ __launch_bounds__(256) void gemm_small_bt(const float* __restrict__ A,
                                                     const float* __restrict__ B,
                                                     float* __restrict__ C, int M, int N, int K) {
  __shared__ float As[16][33];
  __shared__ float Bs[16][33];
  int tid = threadIdx.x;
  int col0 = blockIdx.x * 32;
  int row0 = blockIdx.y * 32;
  int tr = tid >> 4, tc = tid & 15;
  float a00 = 0, a01 = 0, a10 = 0, a11 = 0;
  for (int k0 = 0; k0 < K; k0 += 16) {
    __syncthreads();
    for (int i = tid; i < 512; i += 256) {
      int kk = i & 15, r = i >> 4;
      int row = row0 + r, k = k0 + kk;
      As[kk][r] = (row < M && k < K) ? A[(size_t)row * K + k] : 0.f;
    }
    for (int i = tid; i < 512; i += 256) {
      int kk = i & 15, c = i >> 4;
      int col = col0 + c, k = k0 + kk;
      Bs[kk][c] = (col < N && k < K) ? B[(size_t)col * K + k] : 0.f;
    }
    __syncthreads();
#pragma unroll
    for (int kk = 0; kk < 16; kk++) {
      float x0 = As[kk][tr * 2], x1 = As[kk][tr * 2 + 1];
      float y0 = Bs[kk][tc * 2], y1 = Bs[kk][tc * 2 + 1];
      a00 += x0 * y0;
      a01 += x0 * y1;
      a10 += x1 * y0;
      a11 += x1 * y1;
    }
  }
  int row = row0 + tr * 2, col = col0 + tc * 2;
  if (row < M && col < N) C[(size_t)row * N + col] = a00;
  if (row < M && col + 1 < N) C[(size_t)row * N + col + 1] = a01;
  if (row + 1 < M && col < N) C[(size_t)(row + 1) * N + col] = a10;
  if (row + 1 < M && col + 1 < N) C[(size_t)(row + 1) * N + col + 1] = a11;
}

// block per relation: GRU gates + l2norm, h0 updated in place
__global__ void gru_gate_kernel(const float* __restrict__ gi, const float* __restrict__ gh,
                                const float* __restrict__ b_ih, const float* __restrict__ b_hh,
                                float* __restrict__ h0) {
  int r = blockIdx.x;
  int tid = threadIdx.x;  // 256
  int lane = tid & 63, w = tid >> 6;
  __shared__ float red[4];
  float o = 0.f;
  if (tid < DD) {
    size_t b = (size_t)r * (3 * DD);
    float ir = gi[b + tid] + b_ih[tid];
    float iz = gi[b + DD + tid] + b_ih[DD + tid];
    float inn = gi[b + 2 * DD + tid] + b_ih[2 * DD + tid];
    float hr = gh[b + tid] + b_hh[tid];
    float hz = gh[b + DD + tid] + b_hh[DD + tid];
    float hn = gh[b + 2 * DD + tid] + b_hh[2 * DD + tid];
    float hv = h0[(size_t)r * DD + tid];
    float rr = sigm(ir + hr);
    float z = sigm(iz + hz);
    float n = tanhf(inn + rr * hn);
    o = (1.f - z) * n + z * hv;
  }
  float ss = o * o;
#pragma unroll
  for (int off = 32; off; off >>= 1) ss += __shfl_down(ss, off);
  if (lane == 0) red[w] = ss;
  __syncthreads();
  float tot = red[0] + red[1] + red[2] + red[3];
  float inv = 1.f / fmaxf(sqrtf(tot), 1e-12f);
  if (tid < DD) h0[(size_t)r * DD + tid] = o * inv;
}

// wave per node: aggb[n] = bf16( norm[n] * sum_{e->n} (hh[src]+h0[et]) ), rows padded to 224
__global__ void agg_kernel(const float* __restrict__ hh, const float* __restrict__ h0,
                           const int* __restrict__ rowptr, const int* __restrict__ sorted_edge_t,
                           const int* __restrict__ src_t, const int* __restrict__ et_t,
                           const float* __restrict__ normv_t, short* __restrict__ aggb) {
  int w = threadIdx.x >> 6, lane = threadIdx.x & 63;
  int n = blockIdx.x * 4 + w;
  if (n >= NE) return;
  int beg = rowptr[n], end = rowptr[n + 1];
  float a0 = 0, a1 = 0, a2 = 0, a3 = 0;
  for (int i = beg; i < end; i++) {
    int e = sorted_edge_t[i];
    const float* hr = hh + (size_t)src_t[e] * DD;
    const float* qr = h0 + (size_t)et_t[e] * DD;
    a0 += hr[lane] + qr[lane];
    a1 += hr[64 + lane] + qr[64 + lane];
    a2 += hr[128 + lane] + qr[128 + lane];
    if (lane < 8) a3 += hr[192 + lane] + qr[192 + lane];
  }
  float nm = normv_t[n];
  short* outp = aggb + (size_t)n * APAD;
  outp[lane] = f2bf(a0 * nm);
  outp[64 + lane] = f2bf(a1 * nm);
  outp[128 + lane] = f2bf(a2 * nm);
  if (lane < 8) outp[192 + lane] = f2bf(a3 * nm);
  else if (lane < 32) outp[192 + lane] = 0;  // zero pad cols 200..223
}

// ---------- persistent-B MFMA GEMMs ----------
// 256 blocks x 512 threads (8 waves). Full weight matrices staged to LDS ONCE
// (dual: 2x200x200 bf16 = 160000 B; single: 80000 B), ONE barrier, then waves
// grid-stride over 16-row tiles (3125 total) with zero further sync.
// Col-tiles: ct<12 -> cols ct*16..; ct==12 -> cols 184..199 (overlap; dup cols
// write identical values). Chunk c==6, quad>0 reads k>=200: A frags are zero
// there, B read clamped to a valid address (product is 0 regardless).

__device__ __forceinline__ short8 ldA_f32(const float* __restrict__ ap) {
  float4v v0 = *(const float4v*)ap;
  float4v v1 = *(const float4v*)(ap + 4);
  short tmp[8] = {f2bf(v0[0]), f2bf(v0[1]), f2bf(v0[2]), f2bf(v0[3]),
                  f2bf(v1[0]), f2bf(v1[1]), f2bf(v1[2]), f2bf(v1[3])};
  return *(short8*)&tmp[0];
}

// dual fused: C = rrelu(A1(bf16)@Wb1 + A2(fp32->bf16)@Wb2), fp32 out
__global__ __launch_bounds__(512, 2) void gemm_dual(const short* __restrict__ A1,
                                                    const short* __restrict__ Wb1,
                                                    const float* __restrict__ A2,
                                                    const short* __restrict__ Wb2,
                                                    float* __restrict__ C) {
  __shared__ __align__(16) short Bt[2][200][200];  // 160000 B
  int tid = threadIdx.x;
  for (int s = tid; s < 10000; s += 512) {  // 2 matrices x 200 cols x 25 short8
    int m = s >= 5000;
    int ss = s - m * 5000;
    int n = ss / 25, k8 = (ss - n * 25) * 8;
    const short* W = m ? Wb2 : Wb1;
    *(short8*)&Bt[m][n][k8] = *(const short8*)&W[(size_t)n * WPAD + k8];
  }
  __syncthreads();
  int lane = tid & 63, w = tid >> 6;
  int quad = lane >> 4, l16 = lane & 15;
  for (int ti = w * 256 + blockIdx.x; ti < NTILE; ti += 2048) {
    int arow = ti * 16 + l16;  // < 50000 always
    short8 af1[7], af2[7];
#pragma unroll
    for (int c = 0; c < 7; c++)
      af1[c] = *(const short8*)(A1 + (size_t)arow * APAD + c * 32 + quad * 8);
#pragma unroll
    for (int c = 0; c < 7; c++) {
      int kb = c * 32 + quad * 8;
      af2[c] = (kb < DD) ? ldA_f32(A2 + (size_t)arow * DD + kb) : (short8){0, 0, 0, 0, 0, 0, 0, 0};
    }
    float4v acc[13];
#pragma unroll
    for (int ct = 0; ct < 13; ct++) acc[ct] = (float4v){0.f, 0.f, 0.f, 0.f};
#pragma unroll
    for (int c = 0; c < 7; c++) {
      int kb = (c == 6 && quad > 0) ? quad * 8 : c * 32 + quad * 8;  // clamp (A=0 there)
#pragma unroll
      for (int ct = 0; ct < 13; ct++) {
        int col = (ct < 12 ? ct * 16 : 184) + l16;
        short8 b1 = *(const short8*)&Bt[0][col][kb];
        short8 b2 = *(const short8*)&Bt[1][col][kb];
        acc[ct] = __builtin_amdgcn_mfma_f32_16x16x32_bf16(af1[c], b1, acc[ct], 0, 0, 0);
        acc[ct] = __builtin_amdgcn_mfma_f32_16x16x32_bf16(af2[c], b2, acc[ct], 0, 0, 0);
      }
    }
    int r0 = ti * 16 + quad * 4;
#pragma unroll
    for (int ct = 0; ct < 13; ct++) {
      int col = (ct < 12 ? ct * 16 : 184) + l16;
#pragma unroll
      for (int i = 0; i < 4; i++) {
        float v = acc[ct][i];
        v = (v >= 0.f) ? v : v * SLOPE;
        C[(size_t)(r0 + i) * DD + col] = v;
      }
    }
  }
}

// time-gate GEMM with fused finalize:
// acc = A(hcur)@Wtg; tw = sigm(acc+tgb); cur = l2norm(hh row); out = tw*cur+(1-tw)*A
__global__ __launch_bounds__(512, 4) void gemm_tgfin(const float* __restrict__ A,
                                                     const short* __restrict__ Wb,
                                                     const float* __restrict__ hh,
                                                     const float* __restrict__ tgb,
                                                     float* __restrict__ outp) {
  __shared__ __align__(16) short Bt[200][200];  // 80000 B
  int tid = threadIdx.x;
  for (int s = tid; s < 5000; s += 512) {
    int n = s / 25, k8 = (s - n * 25) * 8;
    *(short8*)&Bt[n][k8] = *(const short8*)&Wb[(size_t)n * WPAD + k8];
  }
  __syncthreads();
  int lane = tid & 63, w = tid >> 6;
  int quad = lane >> 4, l16 = lane & 15;
  for (int ti = w * 256 + blockIdx.x; ti < NTILE; ti += 2048) {
    int arow = ti * 16 + l16;
    short8 af[7];
#pragma unroll
    for (int c = 0; c < 7; c++) {
      int kb = c * 32 + quad * 8;
      af[c] = (kb < DD) ? ldA_f32(A + (size_t)arow * DD + kb) : (short8){0, 0, 0, 0, 0, 0, 0, 0};
    }
    float4v acc[13];
#pragma unroll
    for (int ct = 0; ct < 13; ct++) acc[ct] = (float4v){0.f, 0.f, 0.f, 0.f};
#pragma unroll
    for (int c = 0; c < 7; c++) {
      int kb = (c == 6 && quad > 0) ? quad * 8 : c * 32 + quad * 8;
#pragma unroll
      for (int ct = 0; ct < 13; ct++) {
        int col = (ct < 12 ? ct * 16 : 184) + l16;
        short8 b = *(const short8*)&Bt[col][kb];
        acc[ct] = __builtin_amdgcn_mfma_f32_16x16x32_bf16(af[c], b, acc[ct], 0, 0, 0);
      }
    }
    // fused finalize: per row, l2norm(hh) then gate (ct==12/l16<8 are dup cols -> skip in ssq)
    int rbase = ti * 16 + quad * 4;
#pragma unroll
    for (int i = 0; i < 4; i++) {
      int r = rbase + i;
      size_t rb = (size_t)r * DD;
      float ssq = 0.f;
#pragma unroll
      for (int ct = 0; ct < 13; ct++) {
        int col = (ct < 12 ? ct * 16 : 184) + l16;
        float x = (ct == 12 && l16 < 8) ? 0.f : hh[rb + col];
        ssq += x * x;
      }
#pragma unroll
      for (int off = 1; off < 16; off <<= 1) ssq += __shfl_xor(ssq, off);
      float inv = 1.f / fmaxf(sqrtf(ssq), 1e-12f);
#pragma unroll
      for (int ct = 0; ct < 13; ct++) {
        int col = (ct < 12 ? ct * 16 : 184) + l16;
        float cur = hh[rb + col] * inv;
        float tw = sigm(acc[ct][i] + tgb[col]);
        outp[rb + col] = tw * cur + (1.f - tw) * A[rb + col];
      }
    }
  }
}

// ---------- launch ----------

extern "C" void kernel_launch(void* const* d_in, const int* in_sizes, int n_in, void* d_out,
                              int out_size, void* d_ws, size_t ws_size, hipStream_t stream) {
  const int* src = (const int*)d_in[0];
  const int* dst = (const int*)d_in[1];
  const int* et = (const int*)d_in[2];
  const float* dyn = (const float*)d_in[3];
  const float* emb_rel = (const float*)d_in[4];
  const float* W_ih = (const float*)d_in[5];
  const float* W_hh = (const float*)d_in[6];
  const float* b_ih = (const float*)d_in[7];
  const float* b_hh = (const float*)d_in[8];
  const float* W_nb = (const float*)d_in[9];
  const float* W_lp = (const float*)d_in[10];
  const float* Wtg = (const float*)d_in[11];
  const float* tgb = (const float*)d_in[12];
  float* out = (float*)d_out;

  char* p = (char*)d_ws;
  float* h = (float*)p;        p += (size_t)NE * DD * 4;    // t=0 input
  float* bufB = (float*)p;     p += (size_t)NE * DD * 4;    // layer-1 out; gi/gh alias here
  float* agg = (float*)p;      p += (size_t)NE * DD * 4;    // bf16 agg lives here
  float* h0 = (float*)p;       p += (size_t)R2C * DD * 4;
  float* X = (float*)p;        p += (size_t)R2C * 400 * 4;  // [emb_rel | xmean]
  float* normv = (float*)p;    p += (size_t)TT * NE * 4;
  int* et_rowptr = (int*)p;    p += (size_t)TT * (R2C + 1) * 4;
  int* et_cursor = (int*)p;    p += (size_t)TT * R2C * 4;
  int* et_hist = (int*)p;      p += (size_t)TT * R2C * 4;
  int* sorted_ent = (int*)p;   p += (size_t)TT * 2 * EE * 4;
  int* dst_rowptr = (int*)p;   p += (size_t)TT * (NE + 1) * 4;
  int* dst_cursor = (int*)p;   p += (size_t)TT * NE * 4;
  int* deg_hist = (int*)p;     p += (size_t)TT * NE * 4;
  int* sorted_edge = (int*)p;  p += (size_t)TT * EE * 4;
  short* Wb = (short*)p;       p += (size_t)5 * WSZ * 2;    // pre-converted weights
  float* Xpart = (float*)p;    p += (size_t)R2C * 4 * DD * 4;
  int* csum = (int*)p;         p += (size_t)TT * DNC * 4;

  float* gi = bufB;                          // [480, 600] — bufB dead during GRU phase
  float* gh = bufB + (size_t)R2C * 3 * DD;   // [480, 600]
  short* aggb = (short*)agg;                 // [NE, APAD] bf16

  hipMemsetAsync(et_hist, 0, (size_t)TT * R2C * 4, stream);
  hipMemsetAsync(deg_hist, 0, (size_t)TT * NE * 4, stream);
  hipMemsetAsync(et_cursor, 0, (size_t)TT * R2C * 4, stream);
  hipMemsetAsync(dst_cursor, 0, (size_t)TT * NE * 4, stream);

  init_h_kernel<<<NE, 64, 0, stream>>>(dyn, h);
  copy_kernel<<<(R2C * DD + 255) / 256, 256, 0, stream>>>(emb_rel, h0, R2C * DD);
  fill_x_kernel<<<(R2C * DD + 255) / 256, 256, 0, stream>>>(emb_rel, X);
  prep_w_kernel<<<(5 * WSZ + 255) / 256, 256, 0, stream>>>(W_nb, W_lp, Wtg, Wb);
  const dim3 bin_grid((EE + EPB - 1) / EPB, TT);
  hist_kernel<<<bin_grid, 256, 0, stream>>>(et, dst, et_hist, deg_hist);
  scan_rel_kernel<<<TT, 512, 0, stream>>>(et_hist, et_rowptr);
  const dim3 deg_grid(DNC, TT);
  deg_partial_kernel<<<deg_grid, 256, 0, stream>>>(deg_hist, csum);
  deg_emit_kernel<<<deg_grid, 256, 0, stream>>>(deg_hist, csum, dst_rowptr, normv);
  scatter_rel_kernel<<<bin_grid, 256, 0, stream>>>(src, dst, et, et_rowptr, et_cursor, sorted_ent);
  scatter_dst_kernel<<<(TT * EE + 255) / 256, 256, 0, stream>>>(dst, dst_rowptr, dst_cursor,
                                                                sorted_edge);

  const dim3 gru_grid((3 * DD + 31) / 32, (R2C + 31) / 32);
  const dim3 rm_grid(R2C, 4);
  for (int t = 0; t < TT; t++) {
    const int* src_t = src + (size_t)t * EE;
    const int* et_t = et + (size_t)t * EE;
    const float* hcur = (t == 0) ? h : out + (size_t)(t - 1) * NE * DD;  // carried h
    float* bufA = out + (size_t)t * NE * DD;  // hist slice doubles as layer-0 scratch

    relmean_part_kernel<<<rm_grid, 256, 0, stream>>>(hcur, et_rowptr + t * (R2C + 1),
                                                     sorted_ent + (size_t)t * 2 * EE, Xpart);
    relmean_comb_kernel<<<R2C, 256, 0, stream>>>(Xpart, et_rowptr + t * (R2C + 1), X);
    // GRU as two small GEMMs + fused gate/l2norm
    gemm_small_bt<<<gru_grid, 256, 0, stream>>>(X, W_ih, gi, R2C, 3 * DD, 2 * DD);
    gemm_small_bt<<<gru_grid, 256, 0, stream>>>(h0, W_hh, gh, R2C, 3 * DD, DD);
    gru_gate_kernel<<<R2C, 256, 0, stream>>>(gi, gh, b_ih, b_hh, h0);
    // layer 0
    agg_kernel<<<(NE + 3) / 4, 256, 0, stream>>>(hcur, h0, dst_rowptr + t * (NE + 1),
                                                 sorted_edge + (size_t)t * EE, src_t, et_t,
                                                 normv + (size_t)t * NE, aggb);
    gemm_dual<<<256, 512, 0, stream>>>(aggb, Wb + 0 * WSZ, hcur, Wb + 2 * WSZ, bufA);
    // layer 1
    agg_kernel<<<(NE + 3) / 4, 256, 0, stream>>>(bufA, h0, dst_rowptr + t * (NE + 1),
                                                 sorted_edge + (size_t)t * EE, src_t, et_t,
                                                 normv + (size_t)t * NE, aggb);
    gemm_dual<<<256, 512, 0, stream>>>(aggb, Wb + 1 * WSZ, bufA, Wb + 3 * WSZ, bufB);
    // time gate + finalize fused: out = sigm(hcur@Wtg+b)*l2norm(bufB) + (1-..)*hcur
    gemm_tgfin<<<256, 512, 0, stream>>>(hcur, Wb + 4 * WSZ, bufB, tgb, bufA);
  }
}

// Round 5
// 1434.531 us; speedup vs baseline: 2.6387x; 2.6387x over previous
//
#include <hip/hip_runtime.h>
#include <math.h>

#define NE 50000
#define R2C 480
#define DD 200
#define TT 4
#define EE 100000
#define SLOPE 0.22916666666666666f

#define SCCH 8            // edges per thread in binned kernels
#define EPB (256 * SCCH)  // edges per block = 2048
#define APAD 224          // padded bf16 row stride for agg (multiple of 32)
#define WPAD 224          // padded bf16 k-stride for pre-converted weights
#define WSZ (208 * WPAD)  // one pre-converted weight matrix (shorts)
#define DCH 4096          // deg-scan chunk (256 threads x 16)
#define DNC ((NE + DCH - 1) / DCH)  // 13
#define RSPL 8            // relmean split factor

typedef short short8 __attribute__((ext_vector_type(8)));
typedef float float4v __attribute__((ext_vector_type(4)));

__device__ __forceinline__ float sigm(float x) { return 1.f / (1.f + expf(-x)); }

__device__ __forceinline__ short f2bf(float f) {  // fp32 -> bf16 RNE
  union { float f; unsigned u; } v;
  v.f = f;
  unsigned r = v.u + 0x7fffu + ((v.u >> 16) & 1u);
  return (short)(r >> 16);
}

// ---------- setup kernels ----------

__global__ void init_h_kernel(const float* __restrict__ emb, float* __restrict__ h) {
  int n = blockIdx.x;            // one 64-lane wave per row
  int lane = threadIdx.x;
  size_t base = (size_t)n * DD;
  float v0 = emb[base + lane];
  float v1 = emb[base + 64 + lane];
  float v2 = emb[base + 128 + lane];
  float v3 = (lane < 8) ? emb[base + 192 + lane] : 0.f;
  float ss = v0 * v0 + v1 * v1 + v2 * v2 + v3 * v3;
#pragma unroll
  for (int off = 32; off; off >>= 1) ss += __shfl_down(ss, off);
  ss = __shfl(ss, 0);
  float inv = 1.f / fmaxf(sqrtf(ss), 1e-12f);
  h[base + lane] = v0 * inv;
  h[base + 64 + lane] = v1 * inv;
  h[base + 128 + lane] = v2 * inv;
  if (lane < 8) h[base + 192 + lane] = v3 * inv;
}

__global__ void copy_kernel(const float* __restrict__ a, float* __restrict__ b, int n) {
  int i = blockIdx.x * blockDim.x + threadIdx.x;
  if (i < n) b[i] = a[i];
}

// X[r][0:200] = emb_rel[r]  (X row stride 400)
__global__ void fill_x_kernel(const float* __restrict__ emb_rel, float* __restrict__ X) {
  int i = blockIdx.x * blockDim.x + threadIdx.x;
  if (i >= R2C * DD) return;
  int r = i / DD, d = i - r * DD;
  X[(size_t)r * 400 + d] = emb_rel[i];
}

// pre-convert 5 weight matrices to bf16, layout [m][n(208)][k(224)], zero-padded
__global__ void prep_w_kernel(const float* __restrict__ Wnb, const float* __restrict__ Wlp,
                              const float* __restrict__ Wtg, short* __restrict__ Wb) {
  int idx = blockIdx.x * 256 + threadIdx.x;
  if (idx >= 5 * WSZ) return;
  int m = idx / WSZ, rem = idx - m * WSZ;
  int n = rem / WPAD, k = rem - n * WPAD;
  const float* s;
  if (m == 0) s = Wnb;
  else if (m == 1) s = Wnb + DD * DD;
  else if (m == 2) s = Wlp;
  else if (m == 3) s = Wlp + DD * DD;
  else s = Wtg;
  float v = (n < DD && k < DD) ? s[(size_t)k * DD + n] : 0.f;
  Wb[idx] = f2bf(v);
}

// LDS-binned et histogram; deg_hist stays global (50k bins, low contention)
__global__ __launch_bounds__(256) void hist_kernel(const int* __restrict__ et,
                                                   const int* __restrict__ dst,
                                                   int* __restrict__ et_hist,
                                                   int* __restrict__ deg_hist) {
  __shared__ int lh[R2C];
  int t = blockIdx.y;
  int tid = threadIdx.x;
  int e0 = blockIdx.x * EPB;
  for (int i = tid; i < R2C; i += 256) lh[i] = 0;
  __syncthreads();
#pragma unroll
  for (int c = 0; c < SCCH; c++) {
    int e = e0 + c * 256 + tid;
    if (e < EE) {
      atomicAdd(&lh[et[(size_t)t * EE + e]], 1);
      atomicAdd(&deg_hist[(size_t)t * NE + dst[(size_t)t * EE + e]], 1);
    }
  }
  __syncthreads();
  for (int i = tid; i < R2C; i += 256)
    if (lh[i]) atomicAdd(&et_hist[t * R2C + i], lh[i]);
}

__global__ void scan_rel_kernel(const int* __restrict__ et_hist, int* __restrict__ rowptr) {
  int t = blockIdx.x;
  int tid = threadIdx.x;  // block 512
  __shared__ int s[512];
  int v = (tid < R2C) ? 2 * et_hist[t * R2C + tid] : 0;
  s[tid] = v;
  __syncthreads();
  for (int off = 1; off < 512; off <<= 1) {
    int x = (tid >= off) ? s[tid - off] : 0;
    __syncthreads();
    s[tid] += x;
    __syncthreads();
  }
  if (tid < R2C) rowptr[t * (R2C + 1) + tid] = s[tid] - v;
  if (tid == 0) rowptr[t * (R2C + 1) + R2C] = 2 * EE;
}

// ---- parallel dst-degree scan: chunk sums, then per-chunk emit ----
__global__ __launch_bounds__(256) void deg_partial_kernel(const int* __restrict__ deg_hist,
                                                          int* __restrict__ csum) {
  int t = blockIdx.y, c = blockIdx.x, tid = threadIdx.x;
  const int* dh = deg_hist + (size_t)t * NE;
  int base = c * DCH + tid * 16;
  int s = 0;
  if (base < NE) {
    int end = base + 16 > NE ? NE : base + 16;
    for (int i = base; i < end; i++) s += dh[i];
  }
  __shared__ int red[256];
  red[tid] = s;
  __syncthreads();
  for (int off = 128; off; off >>= 1) {
    if (tid < off) red[tid] += red[tid + off];
    __syncthreads();
  }
  if (tid == 0) csum[t * DNC + c] = red[0];
}

__global__ __launch_bounds__(256) void deg_emit_kernel(const int* __restrict__ deg_hist,
                                                       const int* __restrict__ csum,
                                                       int* __restrict__ rowptr,
                                                       float* __restrict__ normv) {
  int t = blockIdx.y, c = blockIdx.x, tid = threadIdx.x;
  const int* dh = deg_hist + (size_t)t * NE;
  __shared__ int scan[256];
  __shared__ int soff;
  int base = c * DCH + tid * 16;
  int s = 0;
  if (base < NE) {
    int end = base + 16 > NE ? NE : base + 16;
    for (int i = base; i < end; i++) s += dh[i];
  }
  scan[tid] = s;
  __syncthreads();
  for (int off = 1; off < 256; off <<= 1) {
    int x = (tid >= off) ? scan[tid - off] : 0;
    __syncthreads();
    scan[tid] += x;
    __syncthreads();
  }
  if (tid == 0) {
    int o = 0;
    for (int j = 0; j < c; j++) o += csum[t * DNC + j];
    soff = o;
  }
  __syncthreads();
  int run = soff + scan[tid] - s;
  if (base < NE) {
    int end = base + 16 > NE ? NE : base + 16;
    for (int i = base; i < end; i++) {
      int v = dh[i];
      rowptr[t * (NE + 1) + i] = run;
      normv[(size_t)t * NE + i] = 1.f / fmaxf((float)v, 1.f);
      run += v;
    }
  }
  if (c == 0 && tid == 0) rowptr[t * (NE + 1) + NE] = EE;
}

// LDS-binned scatter: one global atomic per (block, present relation)
__global__ __launch_bounds__(256) void scatter_rel_kernel(const int* __restrict__ src,
                                                          const int* __restrict__ dst,
                                                          const int* __restrict__ et,
                                                          const int* __restrict__ rowptr,
                                                          int* __restrict__ cursor,
                                                          int* __restrict__ sorted_ent) {
  __shared__ int lcnt[R2C];
  __shared__ int lbase[R2C];
  int t = blockIdx.y;
  int tid = threadIdx.x;
  int e0 = blockIdx.x * EPB;
  for (int i = tid; i < R2C; i += 256) lcnt[i] = 0;
  __syncthreads();
  int rels[SCCH];
#pragma unroll
  for (int c = 0; c < SCCH; c++) {
    int e = e0 + c * 256 + tid;
    int r = (e < EE) ? et[(size_t)t * EE + e] : -1;
    rels[c] = r;
    if (r >= 0) atomicAdd(&lcnt[r], 2);
  }
  __syncthreads();
  const int* rp = rowptr + t * (R2C + 1);
  for (int i = tid; i < R2C; i += 256) {
    int c = lcnt[i];
    lbase[i] = rp[i] + (c ? atomicAdd(&cursor[t * R2C + i], c) : 0);
    lcnt[i] = 0;
  }
  __syncthreads();
  int* se = sorted_ent + (size_t)t * 2 * EE;
#pragma unroll
  for (int c = 0; c < SCCH; c++) {
    int r = rels[c];
    if (r >= 0) {
      int e = e0 + c * 256 + tid;
      int off = atomicAdd(&lcnt[r], 2);
      int p = lbase[r] + off;
      se[p] = src[(size_t)t * EE + e];
      se[p + 1] = dst[(size_t)t * EE + e];
    }
  }
}

// writes (src,et) pairs sorted by dst -> agg inner loop loses two dependent gathers
__global__ void scatter_dst_kernel(const int* __restrict__ src, const int* __restrict__ dst,
                                   const int* __restrict__ et, const int* __restrict__ rowptr,
                                   int* __restrict__ cursor, int2* __restrict__ sorted_se) {
  int i = blockIdx.x * blockDim.x + threadIdx.x;
  if (i >= TT * EE) return;
  int t = i / EE;
  int d = dst[i];
  int base = rowptr[t * (NE + 1) + d];
  int p = base + atomicAdd(&cursor[(size_t)t * NE + d], 1);
  sorted_se[(size_t)t * EE + p] = make_int2(src[i], et[i]);
}

// ---------- per-step kernels ----------

// RSPL blocks per relation: partial sums of h rows -> Xpart[r*RSPL+j][200]
__global__ void relmean_part_kernel(const float* __restrict__ h, const int* __restrict__ rowptr,
                                    const int* __restrict__ sorted_ent_t,
                                    float* __restrict__ Xpart) {
  int r = blockIdx.x, j = blockIdx.y;
  int beg = rowptr[r], end = rowptr[r + 1];
  int lane = threadIdx.x & 63, w = threadIdx.x >> 6;
  float a0 = 0, a1 = 0, a2 = 0, a3 = 0;
  for (int i = beg + j * 4 + w; i < end; i += 4 * RSPL) {
    int idx = sorted_ent_t[i];
    const float* row = h + (size_t)idx * DD;
    a0 += row[lane];
    a1 += row[64 + lane];
    a2 += row[128 + lane];
    if (lane < 8) a3 += row[192 + lane];
  }
  __shared__ float part[4][DD];
  part[w][lane] = a0;
  part[w][64 + lane] = a1;
  part[w][128 + lane] = a2;
  if (lane < 8) part[w][192 + lane] = a3;
  __syncthreads();
  for (int d = threadIdx.x; d < DD; d += 256) {
    Xpart[((size_t)r * RSPL + j) * DD + d] = part[0][d] + part[1][d] + part[2][d] + part[3][d];
  }
}

__global__ void relmean_comb_kernel(const float* __restrict__ Xpart,
                                    const int* __restrict__ rowptr, float* __restrict__ X) {
  int r = blockIdx.x;
  int d = threadIdx.x;  // 256
  if (d >= DD) return;
  float s = 0.f;
#pragma unroll
  for (int j = 0; j < RSPL; j++) s += Xpart[((size_t)r * RSPL + j) * DD + d];
  float cnt = fmaxf((float)(rowptr[r + 1] - rowptr[r]), 1.f);
  X[(size_t)r * 400 + 200 + d] = s / cnt;
}

// fused GRU GEMM pair: z=0: gi = X@W_ih^T (K=400); z=1: gh = h0@W_hh^T (K=200)
// tile 32x32, K-chunk 32, 2x2/thread
__global__ __launch_bounds__(256) void gemm_gru(const float* __restrict__ X,
                                                const float* __restrict__ h0,
                                                const float* __restrict__ W_ih,
                                                const float* __restrict__ W_hh,
                                                float* __restrict__ gi) {
  int z = blockIdx.z;
  const float* A = z ? h0 : X;
  const float* B = z ? W_hh : W_ih;
  float* C = gi + (size_t)z * R2C * 600;
  int K = z ? DD : 2 * DD;
  const int M = R2C, N = 600;
  __shared__ float As[32][33];
  __shared__ float Bs[32][33];
  int tid = threadIdx.x;
  int col0 = blockIdx.x * 32;
  int row0 = blockIdx.y * 32;
  int tr = tid >> 4, tc = tid & 15;
  float a00 = 0, a01 = 0, a10 = 0, a11 = 0;
  for (int k0 = 0; k0 < K; k0 += 32) {
    __syncthreads();
    for (int i = tid; i < 1024; i += 256) {
      int kk = i & 31, r = i >> 5;
      int row = row0 + r, k = k0 + kk;
      As[kk][r] = (row < M && k < K) ? A[(size_t)row * K + k] : 0.f;
    }
    for (int i = tid; i < 1024; i += 256) {
      int kk = i & 31, c = i >> 5;
      int col = col0 + c, k = k0 + kk;
      Bs[kk][c] = (col < N && k < K) ? B[(size_t)col * K + k] : 0.f;
    }
    __syncthreads();
#pragma unroll
    for (int kk = 0; kk < 32; kk++) {
      float x0 = As[kk][tr * 2], x1 = As[kk][tr * 2 + 1];
      float y0 = Bs[kk][tc * 2], y1 = Bs[kk][tc * 2 + 1];
      a00 += x0 * y0;
      a01 += x0 * y1;
      a10 += x1 * y0;
      a11 += x1 * y1;
    }
  }
  int row = row0 + tr * 2, col = col0 + tc * 2;
  if (row < M && col < N) C[(size_t)row * N + col] = a00;
  if (row < M && col + 1 < N) C[(size_t)row * N + col + 1] = a01;
  if (row + 1 < M && col < N) C[(size_t)(row + 1) * N + col] = a10;
  if (row + 1 < M && col + 1 < N) C[(size_t)(row + 1) * N + col + 1] = a11;
}

// block per relation: GRU gates + l2norm, h0 updated in place
__global__ void gru_gate_kernel(const float* __restrict__ gi, const float* __restrict__ gh,
                                const float* __restrict__ b_ih, const float* __restrict__ b_hh,
                                float* __restrict__ h0) {
  int r = blockIdx.x;
  int tid = threadIdx.x;  // 256
  int lane = tid & 63, w = tid >> 6;
  __shared__ float red[4];
  float o = 0.f;
  if (tid < DD) {
    size_t b = (size_t)r * (3 * DD);
    float ir = gi[b + tid] + b_ih[tid];
    float iz = gi[b + DD + tid] + b_ih[DD + tid];
    float inn = gi[b + 2 * DD + tid] + b_ih[2 * DD + tid];
    float hr = gh[b + tid] + b_hh[tid];
    float hz = gh[b + DD + tid] + b_hh[DD + tid];
    float hn = gh[b + 2 * DD + tid] + b_hh[2 * DD + tid];
    float hv = h0[(size_t)r * DD + tid];
    float rr = sigm(ir + hr);
    float z = sigm(iz + hz);
    float n = tanhf(inn + rr * hn);
    o = (1.f - z) * n + z * hv;
  }
  float ss = o * o;
#pragma unroll
  for (int off = 32; off; off >>= 1) ss += __shfl_down(ss, off);
  if (lane == 0) red[w] = ss;
  __syncthreads();
  float tot = red[0] + red[1] + red[2] + red[3];
  float inv = 1.f / fmaxf(sqrtf(tot), 1e-12f);
  if (tid < DD) h0[(size_t)r * DD + tid] = o * inv;
}

// wave per node: aggb[n] = bf16( norm[n] * sum_{e->n} (hh[src]+h0[et]) ), rows padded to 224
__global__ void agg_kernel(const float* __restrict__ hh, const float* __restrict__ h0,
                           const int* __restrict__ rowptr, const int2* __restrict__ se_t,
                           const float* __restrict__ normv_t, short* __restrict__ aggb) {
  int w = threadIdx.x >> 6, lane = threadIdx.x & 63;
  int n = blockIdx.x * 4 + w;
  if (n >= NE) return;
  int beg = rowptr[n], end = rowptr[n + 1];
  float a0 = 0, a1 = 0, a2 = 0, a3 = 0;
  for (int i = beg; i < end; i++) {
    int2 p = se_t[i];
    const float* hr = hh + (size_t)p.x * DD;
    const float* qr = h0 + (size_t)p.y * DD;
    a0 += hr[lane] + qr[lane];
    a1 += hr[64 + lane] + qr[64 + lane];
    a2 += hr[128 + lane] + qr[128 + lane];
    if (lane < 8) a3 += hr[192 + lane] + qr[192 + lane];
  }
  float nm = normv_t[n];
  short* outp = aggb + (size_t)n * APAD;
  outp[lane] = f2bf(a0 * nm);
  outp[64 + lane] = f2bf(a1 * nm);
  outp[128 + lane] = f2bf(a2 * nm);
  if (lane < 8) outp[192 + lane] = f2bf(a3 * nm);
  else if (lane < 32) outp[192 + lane] = 0;  // zero pad cols 200..223
}

// ---------- MFMA GEMMs (round-3 proven structure) ----------
// geometry: block = 64 rows x 208 cols, 4 waves; wave: 16 rows x 13 col-tiles of 16.
// A row-fragments preloaded to registers upfront; B staged bf16 in LDS per 32-k chunk.

// dual fused: C = rrelu(A1(bf16)@Wb1 + A2(fp32->bf16)@Wb2), fp32 out
__global__ __launch_bounds__(256) void gemm_dual(const short* __restrict__ A1,
                                                 const short* __restrict__ Wb1,
                                                 const float* __restrict__ A2,
                                                 const short* __restrict__ Wb2,
                                                 float* __restrict__ C) {
  __shared__ short Bt[2][208][40];  // [matrix][col][k], k padded 32->40 (bank spread)
  int tid = threadIdx.x;
  int lane = tid & 63, w = tid >> 6;
  int quad = lane >> 4, l16 = lane & 15;
  int row = blockIdx.x * 64 + w * 16 + l16;  // the A row this lane loads
  bool rok = row < NE;

  // preload all A fragments (7 chunks x 16B/lane each, independent loads)
  short8 af1[7], af2[7];
#pragma unroll
  for (int c = 0; c < 7; c++) {
    af1[c] = rok ? *(const short8*)(A1 + (size_t)row * APAD + c * 32 + quad * 8)
                 : (short8){0, 0, 0, 0, 0, 0, 0, 0};
  }
#pragma unroll
  for (int c = 0; c < 7; c++) {
    int kb = c * 32 + quad * 8;
    short8 a = (short8){0, 0, 0, 0, 0, 0, 0, 0};
    if (rok && kb < DD) {  // DD % 8 == 0 -> chunk fully in or out
      const float* ap = A2 + (size_t)row * DD + kb;
      float4v v0 = *(const float4v*)ap;
      float4v v1 = *(const float4v*)(ap + 4);
      short tmp[8] = {f2bf(v0[0]), f2bf(v0[1]), f2bf(v0[2]), f2bf(v0[3]),
                      f2bf(v1[0]), f2bf(v1[1]), f2bf(v1[2]), f2bf(v1[3])};
      a = *(short8*)&tmp[0];
    }
    af2[c] = a;
  }

  float4v acc[13];
#pragma unroll
  for (int ct = 0; ct < 13; ct++) acc[ct] = (float4v){0.f, 0.f, 0.f, 0.f};

#pragma unroll
  for (int c = 0; c < 7; c++) {
    __syncthreads();
    // stage both B chunks: 2 x 832 short8 slots over 256 threads
#pragma unroll
    for (int it = 0; it < 7; it++) {
      int s = tid + it * 256;
      if (s < 1664) {
        int m = s >= 832;
        int ss = s - m * 832;
        int n = ss % 208, k8 = (ss / 208) * 8;
        const short* Wb = m ? Wb2 : Wb1;
        *(short8*)&Bt[m][n][k8] = *(const short8*)&Wb[(size_t)n * WPAD + c * 32 + k8];
      }
    }
    __syncthreads();
#pragma unroll
    for (int ct = 0; ct < 13; ct++) {
      short8 b1 = *(short8*)&Bt[0][ct * 16 + l16][quad * 8];
      short8 b2 = *(short8*)&Bt[1][ct * 16 + l16][quad * 8];
      acc[ct] = __builtin_amdgcn_mfma_f32_16x16x32_bf16(af1[c], b1, acc[ct], 0, 0, 0);
      acc[ct] = __builtin_amdgcn_mfma_f32_16x16x32_bf16(af2[c], b2, acc[ct], 0, 0, 0);
    }
  }
  // epilogue: C[row=quad*4+i][col=l16] per 16x16 tile, rrelu
  int r0 = blockIdx.x * 64 + w * 16 + quad * 4;
#pragma unroll
  for (int ct = 0; ct < 13; ct++) {
    int col = ct * 16 + l16;
    if (col >= DD) continue;
#pragma unroll
    for (int i = 0; i < 4; i++) {
      int r = r0 + i;
      if (r < NE) {
        float v = acc[ct][i];
        v = (v >= 0.f) ? v : v * SLOPE;
        C[(size_t)r * DD + col] = v;
      }
    }
  }
}

// time-gate GEMM with fused finalize:
// acc = A(hcur)@Wtg; tw = sigm(acc + tgb); cur = l2norm(hh row); out = tw*cur + (1-tw)*A
__global__ __launch_bounds__(256) void gemm_tgfin(const float* __restrict__ A,   // hcur = hprev
                                                  const short* __restrict__ Wb,  // Wtg bf16
                                                  const float* __restrict__ hh,  // layer-1 out
                                                  const float* __restrict__ tgb,
                                                  float* __restrict__ outp) {
  __shared__ short Bt[208][40];
  int tid = threadIdx.x;
  int lane = tid & 63, w = tid >> 6;
  int quad = lane >> 4, l16 = lane & 15;
  int row = blockIdx.x * 64 + w * 16 + l16;
  bool rok = row < NE;

  short8 af[7];
#pragma unroll
  for (int c = 0; c < 7; c++) {
    int kb = c * 32 + quad * 8;
    short8 a = (short8){0, 0, 0, 0, 0, 0, 0, 0};
    if (rok && kb < DD) {
      const float* ap = A + (size_t)row * DD + kb;
      float4v v0 = *(const float4v*)ap;
      float4v v1 = *(const float4v*)(ap + 4);
      short tmp[8] = {f2bf(v0[0]), f2bf(v0[1]), f2bf(v0[2]), f2bf(v0[3]),
                      f2bf(v1[0]), f2bf(v1[1]), f2bf(v1[2]), f2bf(v1[3])};
      a = *(short8*)&tmp[0];
    }
    af[c] = a;
  }

  float4v acc[13];
#pragma unroll
  for (int ct = 0; ct < 13; ct++) acc[ct] = (float4v){0.f, 0.f, 0.f, 0.f};

#pragma unroll
  for (int c = 0; c < 7; c++) {
    __syncthreads();
#pragma unroll
    for (int it = 0; it < 4; it++) {
      int s = tid + it * 256;
      if (s < 832) {
        int n = s % 208, k8 = (s / 208) * 8;
        *(short8*)&Bt[n][k8] = *(const short8*)&Wb[(size_t)n * WPAD + c * 32 + k8];
      }
    }
    __syncthreads();
#pragma unroll
    for (int ct = 0; ct < 13; ct++) {
      short8 bf = *(short8*)&Bt[ct * 16 + l16][quad * 8];
      acc[ct] = __builtin_amdgcn_mfma_f32_16x16x32_bf16(af[c], bf, acc[ct], 0, 0, 0);
    }
  }
  // fused finalize epilogue: per output row, l2norm hh then gate against hcur
  int rbase = blockIdx.x * 64 + w * 16 + quad * 4;
#pragma unroll
  for (int i = 0; i < 4; i++) {
    int r = rbase + i;
    bool ok = r < NE;
    size_t rb = (size_t)r * DD;
    float ssq = 0.f;
#pragma unroll
    for (int ct = 0; ct < 13; ct++) {
      int col = ct * 16 + l16;
      float x = (ok && col < DD) ? hh[rb + col] : 0.f;
      ssq += x * x;
    }
#pragma unroll
    for (int off = 1; off < 16; off <<= 1) ssq += __shfl_xor(ssq, off);
    float inv = 1.f / fmaxf(sqrtf(ssq), 1e-12f);
#pragma unroll
    for (int ct = 0; ct < 13; ct++) {
      int col = ct * 16 + l16;
      if (ok && col < DD) {
        float cur = hh[rb + col] * inv;
        float tw = sigm(acc[ct][i] + tgb[col]);
        outp[rb + col] = tw * cur + (1.f - tw) * A[rb + col];
      }
    }
  }
}

// ---------- launch ----------

extern "C" void kernel_launch(void* const* d_in, const int* in_sizes, int n_in, void* d_out,
                              int out_size, void* d_ws, size_t ws_size, hipStream_t stream) {
  const int* src = (const int*)d_in[0];
  const int* dst = (const int*)d_in[1];
  const int* et = (const int*)d_in[2];
  const float* dyn = (const float*)d_in[3];
  const float* emb_rel = (const float*)d_in[4];
  const float* W_ih = (const float*)d_in[5];
  const float* W_hh = (const float*)d_in[6];
  const float* b_ih = (const float*)d_in[7];
  const float* b_hh = (const float*)d_in[8];
  const float* W_nb = (const float*)d_in[9];
  const float* W_lp = (const float*)d_in[10];
  const float* Wtg = (const float*)d_in[11];
  const float* tgb = (const float*)d_in[12];
  float* out = (float*)d_out;

  char* p = (char*)d_ws;
  float* h = (float*)p;        p += (size_t)NE * DD * 4;    // t=0 input
  float* bufB = (float*)p;     p += (size_t)NE * DD * 4;    // layer-1 out; gi/gh alias here
  float* agg = (float*)p;      p += (size_t)NE * DD * 4;    // bf16 agg lives here
  float* h0 = (float*)p;       p += (size_t)R2C * DD * 4;
  float* X = (float*)p;        p += (size_t)R2C * 400 * 4;  // [emb_rel | xmean]
  float* normv = (float*)p;    p += (size_t)TT * NE * 4;
  int* et_rowptr = (int*)p;    p += (size_t)TT * (R2C + 1) * 4;
  int* et_cursor = (int*)p;    p += (size_t)TT * R2C * 4;
  int* et_hist = (int*)p;      p += (size_t)TT * R2C * 4;
  int* sorted_ent = (int*)p;   p += (size_t)TT * 2 * EE * 4;
  int* dst_rowptr = (int*)p;   p += (size_t)TT * (NE + 1) * 4;
  int* dst_cursor = (int*)p;   p += (size_t)TT * NE * 4;
  int* deg_hist = (int*)p;     p += (size_t)TT * NE * 4;
  int2* sorted_se = (int2*)p;  p += (size_t)TT * EE * 8;    // (src,et) sorted by dst
  short* Wb = (short*)p;       p += (size_t)5 * WSZ * 2;    // pre-converted weights
  float* Xpart = (float*)p;    p += (size_t)R2C * RSPL * DD * 4;
  int* csum = (int*)p;         p += (size_t)TT * DNC * 4;

  float* gi = bufB;                          // [480, 600] — bufB dead during GRU phase
  float* gh = bufB + (size_t)R2C * 3 * DD;   // [480, 600]
  short* aggb = (short*)agg;                 // [NE, APAD] bf16

  hipMemsetAsync(et_hist, 0, (size_t)TT * R2C * 4, stream);
  hipMemsetAsync(deg_hist, 0, (size_t)TT * NE * 4, stream);
  hipMemsetAsync(et_cursor, 0, (size_t)TT * R2C * 4, stream);
  hipMemsetAsync(dst_cursor, 0, (size_t)TT * NE * 4, stream);

  init_h_kernel<<<NE, 64, 0, stream>>>(dyn, h);
  copy_kernel<<<(R2C * DD + 255) / 256, 256, 0, stream>>>(emb_rel, h0, R2C * DD);
  fill_x_kernel<<<(R2C * DD + 255) / 256, 256, 0, stream>>>(emb_rel, X);
  prep_w_kernel<<<(5 * WSZ + 255) / 256, 256, 0, stream>>>(W_nb, W_lp, Wtg, Wb);
  const dim3 bin_grid((EE + EPB - 1) / EPB, TT);
  hist_kernel<<<bin_grid, 256, 0, stream>>>(et, dst, et_hist, deg_hist);
  scan_rel_kernel<<<TT, 512, 0, stream>>>(et_hist, et_rowptr);
  const dim3 deg_grid(DNC, TT);
  deg_partial_kernel<<<deg_grid, 256, 0, stream>>>(deg_hist, csum);
  deg_emit_kernel<<<deg_grid, 256, 0, stream>>>(deg_hist, csum, dst_rowptr, normv);
  scatter_rel_kernel<<<bin_grid, 256, 0, stream>>>(src, dst, et, et_rowptr, et_cursor, sorted_ent);
  scatter_dst_kernel<<<(TT * EE + 255) / 256, 256, 0, stream>>>(src, dst, et, dst_rowptr,
                                                                dst_cursor, sorted_se);

  const int gemm_grid = (NE + 63) / 64;  // 782 blocks
  const dim3 gru_grid((600 + 31) / 32, (R2C + 31) / 32, 2);
  const dim3 rm_grid(R2C, RSPL);
  for (int t = 0; t < TT; t++) {
    const float* hcur = (t == 0) ? h : out + (size_t)(t - 1) * NE * DD;  // carried h
    float* bufA = out + (size_t)t * NE * DD;  // hist slice doubles as layer-0 scratch

    relmean_part_kernel<<<rm_grid, 256, 0, stream>>>(hcur, et_rowptr + t * (R2C + 1),
                                                     sorted_ent + (size_t)t * 2 * EE, Xpart);
    relmean_comb_kernel<<<R2C, 256, 0, stream>>>(Xpart, et_rowptr + t * (R2C + 1), X);
    // GRU: fused GEMM pair + fused gate/l2norm
    gemm_gru<<<gru_grid, 256, 0, stream>>>(X, h0, W_ih, W_hh, gi);
    gru_gate_kernel<<<R2C, 256, 0, stream>>>(gi, gh, b_ih, b_hh, h0);
    // layer 0
    agg_kernel<<<(NE + 3) / 4, 256, 0, stream>>>(hcur, h0, dst_rowptr + t * (NE + 1),
                                                 sorted_se + (size_t)t * EE,
                                                 normv + (size_t)t * NE, aggb);
    gemm_dual<<<gemm_grid, 256, 0, stream>>>(aggb, Wb + 0 * WSZ, hcur, Wb + 2 * WSZ, bufA);
    // layer 1
    agg_kernel<<<(NE + 3) / 4, 256, 0, stream>>>(bufA, h0, dst_rowptr + t * (NE + 1),
                                                 sorted_se + (size_t)t * EE,
                                                 normv + (size_t)t * NE, aggb);
    gemm_dual<<<gemm_grid, 256, 0, stream>>>(aggb, Wb + 1 * WSZ, bufA, Wb + 3 * WSZ, bufB);
    // time gate + finalize fused: out = sigm(hcur@Wtg+b)*l2norm(bufB) + (1-..)*hcur
    gemm_tgfin<<<gemm_grid, 256, 0, stream>>>(hcur, Wb + 4 * WSZ, bufB, tgb, bufA);
  }
}